// Round 3
// baseline (743.790 us; speedup 1.0000x reference)
//
#include <hip/hip_runtime.h>
#include <hip/hip_bf16.h>

typedef __attribute__((ext_vector_type(8))) short short8;
typedef __attribute__((ext_vector_type(4))) short short4v;
typedef __attribute__((ext_vector_type(4))) float f32x4;

__device__ __forceinline__ unsigned short f2bf(float f) {
    union { __hip_bfloat16 b; unsigned short u; } v;
    v.b = __float2bfloat16(f);
    return v.u;
}
__device__ __forceinline__ float bf2f(unsigned short u) {
    return __uint_as_float(((unsigned)u) << 16);
}
__device__ __forceinline__ float gelu_tanh(float x) {
    float u = 0.79788456080286536f * x * (1.0f + 0.044715f * x * x);
    return x * __builtin_amdgcn_rcpf(1.0f + __builtin_exp2f(-2.8853900817779268f * u));
}
__device__ __forceinline__ float sigmoidf(float x) {
    return __builtin_amdgcn_rcpf(1.0f + __builtin_exp2f(-1.4426950408889634f * x));
}
__device__ __forceinline__ int swz(int row, int col) {  // short-index swizzle
    return (row * 64 + col) ^ ((row & 7) << 3);
}

// ---------------- prepack: fp32 weights -> bf16 MFMA fragment layout in ws ----------------
// layout (shorts): W1[m] at m*36864 ; W2[m] at 110592+m*4096 ; GATE(320x64 eff.) at 122880
__global__ __launch_bounds__(256)
void prepack_kernel(const float* __restrict__ w1r, const float* __restrict__ w1c,
                    const float* __restrict__ w1b,
                    const float* __restrict__ w2r, const float* __restrict__ w2c,
                    const float* __restrict__ w2b,
                    const float* __restrict__ gw, unsigned short* __restrict__ ws)
{
    int t = blockIdx.x * 256 + threadIdx.x;
    if (t < 13824) {
        int wi = t / 4608, r = t % 4608;
        const float* src = (wi == 0) ? w1r : (wi == 1) ? w1c : w1b;
        unsigned short* dst = ws + wi * 36864;
        int lane = r & 63;
        int col = ((r >> 6) & 3) * 16 + (lane & 15);
        int k0 = (r >> 8) * 32 + (lane >> 4) * 8;
        #pragma unroll
        for (int j = 0; j < 8; ++j) dst[r * 8 + j] = f2bf(src[(k0 + j) * 64 + col]);
    } else if (t < 15360) {
        int q = t - 13824, wi = q / 512, r = q % 512;
        const float* src = (wi == 0) ? w2r : (wi == 1) ? w2c : w2b;
        unsigned short* dst = ws + 110592 + wi * 4096;
        int lane = r & 63;
        int col = ((r >> 6) & 3) * 16 + (lane & 15);
        int k0 = (r >> 8) * 32 + (lane >> 4) * 8;
        #pragma unroll
        for (int j = 0; j < 8; ++j) dst[r * 8 + j] = f2bf(src[(k0 + j) * 64 + col]);
    } else if (t < 17920) {
        int r = t - 15360;
        unsigned short* dst = ws + 122880;
        int lane = r & 63;
        int col = ((r >> 6) & 3) * 16 + (lane & 15);
        int k0 = (r >> 8) * 32 + (lane >> 4) * 8;
        #pragma unroll
        for (int j = 0; j < 8; ++j) {
            int krow = k0 + j;
            float v;
            if (krow < 128) {
                v = gw[krow * 64 + col];
            } else {
                int c = (krow - 128) >> 6, e = (krow - 128) & 63;
                int lo = 3 * e - 64 * c;
                v = 0.f;
                #pragma unroll
                for (int s = 0; s < 3; ++s) {
                    int dp = lo + s;
                    if (dp >= 0 && dp < 64) v += gw[(128 + dp) * 64 + col];
                }
            }
            dst[r * 8 + j] = f2bf(v);
        }
    }
}

// ================= Kernel 1: the three MLPs, z staged once, UP -> ws =================
// UP layout in ws (shorts, base UPWS_OFF): [b][m][i][64] bf16, m: 0=row 1=col 2=box
#define UPWS_OFF 147456

__global__ __launch_bounds__(576, 4)
void k1_mlp(const float* __restrict__ z,
            const float* __restrict__ b1r, const float* __restrict__ b2r,
            const float* __restrict__ b1c, const float* __restrict__ b2c,
            const float* __restrict__ b1b, const float* __restrict__ b2b,
            const short* __restrict__ wsp, unsigned short* __restrict__ upws)
{
    __shared__ __align__(16) unsigned short zslot[2][9216]; // [cell 0..8][lb 0..15][64] swizzled
    __shared__ __align__(16) unsigned short hscr[9][1024];  // per-wave 16x64 scratch
    const int t = threadIdx.x;
    const int lane = t & 63;
    const int w = t >> 6;
    const int rl = lane & 15;
    const int kg = lane >> 4;
    const int b0 = blockIdx.x * 16;

    const int sub = (w < 3) ? w : (w < 6) ? w - 3 : w - 6;
    const int m = (w < 3) ? 0 : (w < 6) ? 2 : 1;   // row / box / col weight index
    const short* w1p = wsp + m * 36864;
    const short* w2p = wsp + 110592 + m * 4096;
    const float* b1p = (m == 0) ? b1r : (m == 1) ? b1c : b1b;
    const float* b2p = (m == 0) ? b2r : (m == 1) ? b2c : b2b;
    float b1v[4], b2v[4];
    #pragma unroll
    for (int nt = 0; nt < 4; ++nt) { b1v[nt] = b1p[nt * 16 + rl]; b2v[nt] = b2p[nt * 16 + rl]; }

    // staging thread mapping: thread -> (lb, u), covers floats u*16..u*16+15 of the 576-float row
    const int slb = t / 36, su = t % 36;
    const float* zrowbase = z + (size_t)(b0 + slb) * 5184 + su * 16;

    float4 pf[4];
    auto issue = [&](int r) {
        const float* p = zrowbase + r * 576;
        #pragma unroll
        for (int j = 0; j < 4; ++j) pf[j] = *(const float4*)(p + j * 4);
    };
    auto commit = [&](int r) {
        unsigned short* sl = zslot[r & 1];
        #pragma unroll
        for (int j = 0; j < 4; ++j) {
            int fo = su * 16 + j * 4;
            int cell = fo >> 6, f = fo & 63;
            uint2 pk;
            pk.x = ((unsigned)f2bf(pf[j].y) << 16) | f2bf(pf[j].x);
            pk.y = ((unsigned)f2bf(pf[j].w) << 16) | f2bf(pf[j].z);
            *(uint2*)&sl[swz(cell * 16 + slb, f)] = pk;
        }
    };

    // persistent accumulators
    f32x4 bacc[4], cacc[3][4];
    #pragma unroll
    for (int nt = 0; nt < 4; ++nt) {
        bacc[nt] = (f32x4)0.f;
        #pragma unroll
        for (int tt = 0; tt < 3; ++tt) cacc[tt][nt] = (f32x4)0.f;
    }

    auto flush = [&](int i, f32x4* acc) {
        // gelu+bias -> hscr (C-layout: lane holds rows lb=kg*4+reg, col n=nt*16+rl)
        #pragma unroll
        for (int nt = 0; nt < 4; ++nt)
            #pragma unroll
            for (int reg = 0; reg < 4; ++reg) {
                int lb = kg * 4 + reg;
                hscr[w][swz(lb, nt * 16 + rl)] = f2bf(gelu_tanh(acc[nt][reg] + b1v[nt]));
            }
        asm volatile("s_waitcnt lgkmcnt(0)" ::: "memory");
        f32x4 a2c[4];
        #pragma unroll
        for (int nt = 0; nt < 4; ++nt) a2c[nt] = (f32x4)0.f;
        #pragma unroll
        for (int kk2 = 0; kk2 < 2; ++kk2) {
            short8 a2 = *(const short8*)&hscr[w][swz(rl, kk2 * 32 + kg * 8)];
            #pragma unroll
            for (int nt = 0; nt < 4; ++nt) {
                short8 bw = *(const short8*)(w2p + ((kk2 * 4 + nt) * 64 + lane) * 8);
                a2c[nt] = __builtin_amdgcn_mfma_f32_16x16x32_bf16(a2, bw, a2c[nt], 0, 0, 0);
            }
        }
        asm volatile("s_waitcnt lgkmcnt(0)" ::: "memory");
        #pragma unroll
        for (int nt = 0; nt < 4; ++nt)
            #pragma unroll
            for (int reg = 0; reg < 4; ++reg) {
                int lb = kg * 4 + reg;
                hscr[w][swz(lb, nt * 16 + rl)] = f2bf(a2c[nt][reg] + b2v[nt]);
            }
        asm volatile("s_waitcnt lgkmcnt(0)" ::: "memory");
        #pragma unroll
        for (int p = 0; p < 2; ++p) {
            int lb = p * 8 + (lane >> 3), f0 = (lane & 7) * 8;
            short8 v = *(const short8*)&hscr[w][swz(lb, f0)];
            *(short8*)(upws + ((size_t)(b0 + lb) * 27 + m * 9 + i) * 64 + f0) = v;
        }
    };

    // prologue: stage row 0
    issue(0); commit(0);
    __syncthreads();

    #pragma unroll
    for (int r = 0; r < 9; ++r) {
        if (r < 8) issue(r + 1);
        const unsigned short* sl = zslot[r & 1];

        if (w < 3) {                       // ---- row waves ----
            if (sub == r % 3) {
                f32x4 acc[4];
                #pragma unroll
                for (int nt = 0; nt < 4; ++nt) acc[nt] = (f32x4)0.f;
                #pragma unroll
                for (int kk = 0; kk < 18; ++kk) {
                    int cell = kk >> 1, f = (kk & 1) * 32 + kg * 8;
                    short8 a = *(const short8*)&sl[swz(cell * 16 + rl, f)];
                    #pragma unroll
                    for (int nt = 0; nt < 4; ++nt) {
                        short8 bv = *(const short8*)(w1p + ((kk * 4 + nt) * 64 + lane) * 8);
                        acc[nt] = __builtin_amdgcn_mfma_f32_16x16x32_bf16(a, bv, acc[nt], 0, 0, 0);
                    }
                }
                flush(r, acc);
            }
        } else if (w < 6) {                // ---- box waves ----
            if (r % 3 == 0) {
                #pragma unroll
                for (int nt = 0; nt < 4; ++nt) bacc[nt] = (f32x4)0.f;
            }
            int i = (r / 3) * 3 + sub;
            #pragma unroll
            for (int tc = 0; tc < 3; ++tc) {
                int col = (i % 3) * 3 + tc;
                int j = (r % 3) * 3 + tc;
                #pragma unroll
                for (int h = 0; h < 2; ++h) {
                    int kk = 2 * j + h, f = h * 32 + kg * 8;
                    short8 a = *(const short8*)&sl[swz(col * 16 + rl, f)];
                    #pragma unroll
                    for (int nt = 0; nt < 4; ++nt) {
                        short8 bv = *(const short8*)(w1p + ((kk * 4 + nt) * 64 + lane) * 8);
                        bacc[nt] = __builtin_amdgcn_mfma_f32_16x16x32_bf16(a, bv, bacc[nt], 0, 0, 0);
                    }
                }
            }
            if (r % 3 == 2) flush(i, bacc);
        } else {                           // ---- col waves ----
            #pragma unroll
            for (int tt = 0; tt < 3; ++tt) {
                int i = sub + tt * 3;
                #pragma unroll
                for (int h = 0; h < 2; ++h) {
                    int kk = 2 * r + h, f = h * 32 + kg * 8;
                    short8 a = *(const short8*)&sl[swz(i * 16 + rl, f)];
                    #pragma unroll
                    for (int nt = 0; nt < 4; ++nt) {
                        short8 bv = *(const short8*)(w1p + ((kk * 4 + nt) * 64 + lane) * 8);
                        cacc[tt][nt] = __builtin_amdgcn_mfma_f32_16x16x32_bf16(a, bv, cacc[tt][nt], 0, 0, 0);
                    }
                }
            }
            if (r == 8) {
                #pragma unroll
                for (int tt = 0; tt < 3; ++tt) flush(sub + tt * 3, cacc[tt]);
            }
        }
        if (r < 8) commit(r + 1);
        __syncthreads();
    }
}

// ================= Kernel 2: gate GEMM (swapped operands) + epilogue =================
__global__ __launch_bounds__(576, 4)
void k2_gate(const float* __restrict__ z, const unsigned short* __restrict__ upws,
             const short* __restrict__ wsp, const float* __restrict__ gb,
             const float* __restrict__ alphap, float* __restrict__ out)
{
    __shared__ __align__(16) unsigned short ups[27648];  // [b*27 + m*9 + i][64] swizzled
    __shared__ __align__(16) unsigned short tscr[9][1024];
    const int t = threadIdx.x;
    const int lane = t & 63;
    const int w = t >> 6;
    const int rl = lane & 15;
    const int kg = lane >> 4;
    const int b0 = blockIdx.x * 16;

    // stage UP (coalesced 16B chunks)
    #pragma unroll
    for (int c6 = 0; c6 < 6; ++c6) {
        int chunk = t + c6 * 576;
        int row = chunk >> 3, f0 = (chunk & 7) * 8;
        short8 v = *(const short8*)(upws + (size_t)b0 * 1728 + chunk * 8);
        *(short8*)&ups[swz(row, f0)] = v;
    }
    __syncthreads();

    const short* gwp = wsp + 122880;
    const float alpha = alphap[0];
    float gbl[4][4];
    #pragma unroll
    for (int mt = 0; mt < 4; ++mt)
        #pragma unroll
        for (int reg = 0; reg < 4; ++reg) gbl[mt][reg] = gb[mt * 16 + kg * 4 + reg];

    const int c = w % 3, wg = w / 3;

    #pragma unroll
    for (int tl = 0; tl < 9; ++tl) {
        int e = (wg * 9 + tl) * 16 + rl;
        int b = e / 27, rem = e % 27, R = rem / 3, q = rem % 3, C = c + 3 * q;
        int rowR = b * 27 + R, rowC = b * 27 + 9 + C, rowB = b * 27 + 18 + R;

        f32x4 acc[4];
        #pragma unroll
        for (int mt = 0; mt < 4; ++mt) acc[mt] = (f32x4)0.f;

        #pragma unroll
        for (int s6 = 0; s6 < 6; ++s6) {
            int seg = s6 >> 1;
            int kkp = (s6 < 4) ? s6 : 4 + 2 * c + (s6 - 4);
            int row = (seg == 0) ? rowR : (seg == 1) ? rowC : rowB;
            int f = (s6 & 1) * 32 + kg * 8;
            short8 bfrag = *(const short8*)&ups[swz(row, f)];
            #pragma unroll
            for (int mt = 0; mt < 4; ++mt) {
                short8 afrag = *(const short8*)(gwp + ((kkp * 4 + mt) * 64 + lane) * 8);
                acc[mt] = __builtin_amdgcn_mfma_f32_16x16x32_bf16(afrag, bfrag, acc[mt], 0, 0, 0);
            }
        }

        // t = alpha * sigmoid(S) * delta  -> tscr (bf16), lane = one cell
        #pragma unroll
        for (int mt = 0; mt < 4; ++mt) {
            short4v du4 = *(const short4v*)&ups[swz(rowR, mt * 16 + kg * 4)];
            short4v dc4 = *(const short4v*)&ups[swz(rowC, mt * 16 + kg * 4)];
            #pragma unroll
            for (int reg = 0; reg < 4; ++reg) {
                int fidx = mt * 16 + kg * 4 + reg;
                float g = sigmoidf(acc[mt][reg] + gbl[mt][reg]);
                float duv = bf2f((unsigned short)du4[reg]);
                float dcv = bf2f((unsigned short)dc4[reg]);
                float dbv = bf2f(ups[swz(rowB, (64 * c + fidx) / 3)]);
                tscr[w][swz(rl, fidx)] = f2bf(alpha * g * (duv + dcv + dbv));
            }
        }
        asm volatile("s_waitcnt lgkmcnt(0)" ::: "memory");
        // transposed readback -> fully coalesced float4 out
        #pragma unroll
        for (int p = 0; p < 2; ++p) {
            int cl = p * 8 + (lane >> 3), f0 = (lane & 7) * 8;
            int e2 = (wg * 9 + tl) * 16 + cl;
            int b2 = e2 / 27, rem2 = e2 % 27, R2 = rem2 / 3, C2 = c + 3 * (rem2 % 3);
            short8 tv = *(const short8*)&tscr[w][swz(cl, f0)];
            const float* zp = z + (size_t)(b0 + b2) * 5184 + (size_t)(R2 * 9 + C2) * 64 + f0;
            float4 z0 = *(const float4*)zp;
            float4 z1 = *(const float4*)(zp + 4);
            float4 o0, o1;
            o0.x = z0.x + bf2f((unsigned short)tv[0]);
            o0.y = z0.y + bf2f((unsigned short)tv[1]);
            o0.z = z0.z + bf2f((unsigned short)tv[2]);
            o0.w = z0.w + bf2f((unsigned short)tv[3]);
            o1.x = z1.x + bf2f((unsigned short)tv[4]);
            o1.y = z1.y + bf2f((unsigned short)tv[5]);
            o1.z = z1.z + bf2f((unsigned short)tv[6]);
            o1.w = z1.w + bf2f((unsigned short)tv[7]);
            float* op = out + (size_t)(b0 + b2) * 5184 + (size_t)(R2 * 9 + C2) * 64 + f0;
            *(float4*)op = o0;
            *(float4*)(op + 4) = o1;
        }
        asm volatile("s_waitcnt lgkmcnt(0)" ::: "memory");
    }
}

// ================= fallback (round-2 kernel) if ws is too small =================
__global__ __launch_bounds__(576, 5)
void fisher_mfma_kernel(const float* __restrict__ z,
                        const float* __restrict__ b1r, const float* __restrict__ b2r,
                        const float* __restrict__ b1c, const float* __restrict__ b2c,
                        const float* __restrict__ b1b, const float* __restrict__ b2b,
                        const float* __restrict__ gb, const float* __restrict__ alphap,
                        const short* __restrict__ wsp,
                        float* __restrict__ out)
{
    __shared__ __align__(16) unsigned short lds[36864];
    const int tid = threadIdx.x;
    const int lane = tid & 63;
    const int wave = tid >> 6;
    const int rl = lane & 15;
    const int kg = lane >> 4;
    const int koff = kg * 8;
    const int b0 = blockIdx.x * 16;
    const int m = wave / 3;
    const int sw = wave % 3;

    const short* w1p = wsp + m * 36864;
    const short* w2p = wsp + 110592 + m * 4096;
    const float* b1p = (m == 0) ? b1r : (m == 1) ? b1c : b1b;
    const float* b2p = (m == 0) ? b2r : (m == 1) ? b2c : b2b;

    int abase[3];
    #pragma unroll
    for (int tt = 0; tt < 3; ++tt) {
        int r = sw * 48 + tt * 16 + rl;
        int lb = r / 9, i = r % 9;
        int ib = (m == 0) ? i * 576 : (m == 1) ? i * 64 : (i / 3) * 1728 + (i % 3) * 192;
        abase[tt] = (b0 + lb) * 5184 + ib;
    }

    f32x4 acc[3][4];
    #pragma unroll
    for (int tt = 0; tt < 3; ++tt)
        #pragma unroll
        for (int nt = 0; nt < 4; ++nt) acc[tt][nt] = (f32x4)0.f;

    static const int boxoff[9] = {0, 64, 128, 576, 640, 704, 1152, 1216, 1280};

    #pragma unroll
    for (int kk = 0; kk < 18; ++kk) {
        const int cell = kk >> 1;
        const int dof = (kk & 1) * 32 + koff;
        const int coff = (m == 0) ? cell * 64 : (m == 1) ? cell * 576 : boxoff[cell];
        short8 a[3];
        #pragma unroll
        for (int tt = 0; tt < 3; ++tt) {
            const float* ap = z + abase[tt] + coff + dof;
            float4 f0 = *(const float4*)ap;
            float4 f1 = *(const float4*)(ap + 4);
            short8 av;
            av[0] = (short)f2bf(f0.x); av[1] = (short)f2bf(f0.y);
            av[2] = (short)f2bf(f0.z); av[3] = (short)f2bf(f0.w);
            av[4] = (short)f2bf(f1.x); av[5] = (short)f2bf(f1.y);
            av[6] = (short)f2bf(f1.z); av[7] = (short)f2bf(f1.w);
            a[tt] = av;
        }
        #pragma unroll
        for (int nt = 0; nt < 4; ++nt) {
            short8 bv = *(const short8*)(w1p + ((kk * 4 + nt) * 64 + lane) * 8);
            #pragma unroll
            for (int tt = 0; tt < 3; ++tt)
                acc[tt][nt] = __builtin_amdgcn_mfma_f32_16x16x32_bf16(a[tt], bv, acc[tt][nt], 0, 0, 0);
        }
    }

    float b1v[4], b2v[4];
    #pragma unroll
    for (int nt = 0; nt < 4; ++nt) { b1v[nt] = b1p[nt * 16 + rl]; b2v[nt] = b2p[nt * 16 + rl]; }
    const int upoff = (m == 0) ? 9216 : (m == 1) ? 18432 : 27648;
    const int hoff = wave * 1024;

    #pragma unroll
    for (int tt = 0; tt < 3; ++tt) {
        asm volatile("s_waitcnt lgkmcnt(0)" ::: "memory");
        #pragma unroll
        for (int nt = 0; nt < 4; ++nt)
            #pragma unroll
            for (int reg = 0; reg < 4; ++reg) {
                int hrow = kg * 4 + reg, col = nt * 16 + rl;
                lds[hoff + swz(hrow, col)] = f2bf(gelu_tanh(acc[tt][nt][reg] + b1v[nt]));
            }
        asm volatile("s_waitcnt lgkmcnt(0)" ::: "memory");
        f32x4 acc2[4];
        #pragma unroll
        for (int nt = 0; nt < 4; ++nt) acc2[nt] = (f32x4)0.f;
        #pragma unroll
        for (int kk2 = 0; kk2 < 2; ++kk2) {
            short8 a2 = *(const short8*)&lds[hoff + swz(rl, kk2 * 32 + koff)];
            #pragma unroll
            for (int nt = 0; nt < 4; ++nt) {
                short8 bw = *(const short8*)(w2p + ((kk2 * 4 + nt) * 64 + lane) * 8);
                acc2[nt] = __builtin_amdgcn_mfma_f32_16x16x32_bf16(a2, bw, acc2[nt], 0, 0, 0);
            }
        }
        #pragma unroll
        for (int nt = 0; nt < 4; ++nt)
            #pragma unroll
            for (int reg = 0; reg < 4; ++reg) {
                int row = sw * 48 + tt * 16 + kg * 4 + reg;
                int col = nt * 16 + rl;
                lds[upoff + swz(row, col)] = f2bf(acc2[nt][reg] + b2v[nt]);
            }
    }
    __syncthreads();

    float gbv[4];
    #pragma unroll
    for (int nt = 0; nt < 4; ++nt) gbv[nt] = gb[nt * 16 + rl];
    const float alpha = alphap[0];
    const short* gwp = wsp + 122880;
    const int c = m;

    for (int pass = 0; pass < 3; ++pass) {
        const int tiles0 = sw * 9 + pass * 3;
        int rR[3], rC[3];
        #pragma unroll
        for (int tt = 0; tt < 3; ++tt) {
            int r = (tiles0 + tt) * 16 + rl;
            int lb = r / 27, j = r % 27;
            rR[tt] = lb * 9 + j / 3;
            rC[tt] = lb * 9 + c + 3 * (j % 3);
        }
        f32x4 ag[3][4];
        #pragma unroll
        for (int tt = 0; tt < 3; ++tt)
            #pragma unroll
            for (int nt = 0; nt < 4; ++nt) ag[tt][nt] = (f32x4)0.f;

        #pragma unroll
        for (int s6 = 0; s6 < 6; ++s6) {
            const int kkp = (s6 < 4) ? s6 : 4 + 2 * c + (s6 - 4);
            const int ko = (s6 & 1) * 32 + koff;
            const int region = (s6 < 2) ? 9216 : (s6 < 4) ? 18432 : 27648;
            short8 a[3];
            #pragma unroll
            for (int tt = 0; tt < 3; ++tt) {
                int lr = (s6 >= 2 && s6 < 4) ? rC[tt] : rR[tt];
                a[tt] = *(const short8*)&lds[region + swz(lr, ko)];
            }
            #pragma unroll
            for (int nt = 0; nt < 4; ++nt) {
                short8 bv = *(const short8*)(gwp + ((kkp * 4 + nt) * 64 + lane) * 8);
                #pragma unroll
                for (int tt = 0; tt < 3; ++tt)
                    ag[tt][nt] = __builtin_amdgcn_mfma_f32_16x16x32_bf16(a[tt], bv, ag[tt][nt], 0, 0, 0);
            }
        }
        #pragma unroll
        for (int tt = 0; tt < 3; ++tt)
            #pragma unroll
            for (int reg = 0; reg < 4; ++reg) {
                int r = (tiles0 + tt) * 16 + kg * 4 + reg;
                int lb = r / 27, j = r % 27;
                int R = j / 3, C = c + 3 * (j % 3);
                size_t zoff = (size_t)(b0 + lb) * 5184 + (size_t)(R * 9 + C) * 64;
                int rowR = lb * 9 + R, rowC = lb * 9 + C;
                #pragma unroll
                for (int nt = 0; nt < 4; ++nt) {
                    int d = nt * 16 + rl;
                    float g = sigmoidf(ag[tt][nt][reg] + gbv[nt]);
                    float du = bf2f(lds[9216 + swz(rowR, d)]);
                    float dc = bf2f(lds[18432 + swz(rowC, d)]);
                    float db = bf2f(lds[27648 + swz(rowR, (64 * c + d) / 3)]);
                    float zv = z[zoff + d];
                    out[zoff + d] = zv + alpha * g * (du + dc + db);
                }
            }
    }
}

extern "C" void kernel_launch(void* const* d_in, const int* in_sizes, int n_in,
                              void* d_out, int out_size, void* d_ws, size_t ws_size,
                              hipStream_t stream) {
    const float* z   = (const float*)d_in[0];
    const float* w1r = (const float*)d_in[1];
    const float* b1r = (const float*)d_in[2];
    const float* w2r = (const float*)d_in[3];
    const float* b2r = (const float*)d_in[4];
    const float* w1c = (const float*)d_in[5];
    const float* b1c = (const float*)d_in[6];
    const float* w2c = (const float*)d_in[7];
    const float* b2c = (const float*)d_in[8];
    const float* w1b = (const float*)d_in[9];
    const float* b1b = (const float*)d_in[10];
    const float* w2b = (const float*)d_in[11];
    const float* b2b = (const float*)d_in[12];
    const float* gw  = (const float*)d_in[13];
    const float* gb  = (const float*)d_in[14];
    const float* al  = (const float*)d_in[15];
    float* outp = (float*)d_out;
    unsigned short* ws = (unsigned short*)d_ws;

    const int Btot = in_sizes[0] / 5184;     // 8192
    const size_t ws_needed = (size_t)UPWS_OFF * 2 + (size_t)Btot * 27 * 64 * 2;

    prepack_kernel<<<70, 256, 0, stream>>>(w1r, w1c, w1b, w2r, w2c, w2b, gw, ws);

    if (ws_size >= ws_needed) {
        unsigned short* upws = ws + UPWS_OFF;
        k1_mlp<<<Btot / 16, 576, 0, stream>>>(z, b1r, b2r, b1c, b2c, b1b, b2b,
                                              (const short*)ws, upws);
        k2_gate<<<Btot / 16, 576, 0, stream>>>(z, upws, (const short*)ws, gb, al, outp);
    } else {
        fisher_mfma_kernel<<<Btot / 16, 576, 0, stream>>>(
            z, b1r, b2r, b1c, b2c, b1b, b2b, gb, al, (const short*)ws, outp);
    }
}

// Round 4
// 563.427 us; speedup vs baseline: 1.3201x; 1.3201x over previous
//
#include <hip/hip_runtime.h>
#include <hip/hip_bf16.h>

typedef __attribute__((ext_vector_type(8))) short short8;
typedef __attribute__((ext_vector_type(4))) float f32x4;

__device__ __forceinline__ unsigned short f2bf(float f) {
    union { __hip_bfloat16 b; unsigned short u; } v;
    v.b = __float2bfloat16(f);
    return v.u;
}
__device__ __forceinline__ float bf2f(unsigned short u) {
    return __uint_as_float(((unsigned)u) << 16);
}
__device__ __forceinline__ float gelu_tanh(float x) {
    float u = 0.79788456080286536f * x * (1.0f + 0.044715f * x * x);
    return x * __builtin_amdgcn_rcpf(1.0f + __builtin_exp2f(-2.8853900817779268f * u));
}
__device__ __forceinline__ float sigmoidf(float x) {
    return __builtin_amdgcn_rcpf(1.0f + __builtin_exp2f(-1.4426950408889634f * x));
}
__device__ __forceinline__ int swz(int row, int col) {  // short-index swizzle
    return (row * 64 + col) ^ ((row & 7) << 3);
}

// ---------------- prepack: fp32 weights -> bf16 MFMA fragment layout in ws ----------------
// layout (shorts): W1[m] at m*36864 ; W2[m] at 110592+m*4096 ; GATE(320x64 eff.) at 122880
__global__ __launch_bounds__(256)
void prepack_kernel(const float* __restrict__ w1r, const float* __restrict__ w1c,
                    const float* __restrict__ w1b,
                    const float* __restrict__ w2r, const float* __restrict__ w2c,
                    const float* __restrict__ w2b,
                    const float* __restrict__ gw, unsigned short* __restrict__ ws)
{
    int t = blockIdx.x * 256 + threadIdx.x;
    if (t < 13824) {
        int wi = t / 4608, r = t % 4608;
        const float* src = (wi == 0) ? w1r : (wi == 1) ? w1c : w1b;
        unsigned short* dst = ws + wi * 36864;
        int lane = r & 63;
        int col = ((r >> 6) & 3) * 16 + (lane & 15);
        int k0 = (r >> 8) * 32 + (lane >> 4) * 8;
        #pragma unroll
        for (int j = 0; j < 8; ++j) dst[r * 8 + j] = f2bf(src[(k0 + j) * 64 + col]);
    } else if (t < 15360) {
        int q = t - 13824, wi = q / 512, r = q % 512;
        const float* src = (wi == 0) ? w2r : (wi == 1) ? w2c : w2b;
        unsigned short* dst = ws + 110592 + wi * 4096;
        int lane = r & 63;
        int col = ((r >> 6) & 3) * 16 + (lane & 15);
        int k0 = (r >> 8) * 32 + (lane >> 4) * 8;
        #pragma unroll
        for (int j = 0; j < 8; ++j) dst[r * 8 + j] = f2bf(src[(k0 + j) * 64 + col]);
    } else if (t < 17920) {
        int r = t - 15360;
        unsigned short* dst = ws + 122880;
        int lane = r & 63;
        int col = ((r >> 6) & 3) * 16 + (lane & 15);
        int k0 = (r >> 8) * 32 + (lane >> 4) * 8;
        #pragma unroll
        for (int j = 0; j < 8; ++j) {
            int krow = k0 + j;
            float v;
            if (krow < 128) {
                v = gw[krow * 64 + col];
            } else {
                int c = (krow - 128) >> 6, e = (krow - 128) & 63;
                int lo = 3 * e - 64 * c;
                v = 0.f;
                #pragma unroll
                for (int s = 0; s < 3; ++s) {
                    int dp = lo + s;
                    if (dp >= 0 && dp < 64) v += gw[(128 + dp) * 64 + col];
                }
            }
            dst[r * 8 + j] = f2bf(v);
        }
    }
}

// ---------------- fused kernel: 16 batches/block, 9 waves, z staged once in thirds ----------------
// LDS (shorts): ZS [0,27648) = 27 cells x 16 b x 64 ; UPR/UPC/UPB 9216 each ; H 9x1024
#define ZS    0
#define UPR   27648
#define UPC   36864
#define UPB   46080
#define HB0   55296

#define FLUSH(UPBASE, IIDX, ACC) do {                                                         \
    asm volatile("s_waitcnt lgkmcnt(0)" ::: "memory");                                        \
    _Pragma("unroll")                                                                         \
    for (int nt = 0; nt < 4; ++nt) {                                                          \
        _Pragma("unroll")                                                                     \
        for (int reg = 0; reg < 4; ++reg)                                                     \
            lds[hoff + swz(kg * 4 + reg, nt * 16 + rl)] =                                     \
                f2bf(gelu_tanh(ACC[nt][reg] + b1v[nt]));                                      \
    }                                                                                         \
    asm volatile("s_waitcnt lgkmcnt(0)" ::: "memory");                                        \
    f32x4 a2c[4];                                                                             \
    _Pragma("unroll")                                                                         \
    for (int nt = 0; nt < 4; ++nt) a2c[nt] = (f32x4)0.f;                                      \
    _Pragma("unroll")                                                                         \
    for (int kk2 = 0; kk2 < 2; ++kk2) {                                                       \
        short8 a2 = *(const short8*)&lds[hoff + swz(rl, kk2 * 32 + kg * 8)];                  \
        _Pragma("unroll")                                                                     \
        for (int nt = 0; nt < 4; ++nt) {                                                      \
            short8 bw = *(const short8*)(w2p + ((kk2 * 4 + nt) * 64 + lane) * 8);             \
            a2c[nt] = __builtin_amdgcn_mfma_f32_16x16x32_bf16(a2, bw, a2c[nt], 0, 0, 0);      \
        }                                                                                     \
    }                                                                                         \
    _Pragma("unroll")                                                                         \
    for (int nt = 0; nt < 4; ++nt) {                                                          \
        _Pragma("unroll")                                                                     \
        for (int reg = 0; reg < 4; ++reg)                                                     \
            lds[(UPBASE) + swz((kg * 4 + reg) * 9 + (IIDX), nt * 16 + rl)] =                  \
                f2bf(a2c[nt][reg] + b2v[nt]);                                                 \
    }                                                                                         \
} while (0)

__global__ __launch_bounds__(576, 2)
void fisher_fused(const float* __restrict__ z,
                  const float* __restrict__ b1r, const float* __restrict__ b2r,
                  const float* __restrict__ b1c, const float* __restrict__ b2c,
                  const float* __restrict__ b1b, const float* __restrict__ b2b,
                  const float* __restrict__ gb, const float* __restrict__ alphap,
                  const short* __restrict__ wsp,
                  float* __restrict__ out)
{
    __shared__ __align__(16) unsigned short lds[64512];
    const int t = threadIdx.x;
    const int lane = t & 63;
    const int w = t >> 6;
    const int rl = lane & 15;
    const int kg = lane >> 4;
    const int b0 = blockIdx.x * 16;

    const int role = (w < 3) ? 0 : (w < 6) ? 1 : 2;   // 0=row 1=box 2=col
    const int sub  = (w < 3) ? w : (w < 6) ? w - 3 : w - 6;
    const int m    = (role == 0) ? 0 : (role == 1) ? 2 : 1;  // weight set: 0=row 1=col 2=box
    const int hoff = HB0 + w * 1024;

    const short* w1p = wsp + m * 36864;
    const short* w2p = wsp + 110592 + m * 4096;
    const float* b1p = (m == 0) ? b1r : (m == 1) ? b1c : b1b;
    const float* b2p = (m == 0) ? b2r : (m == 1) ? b2c : b2b;
    float b1v[4], b2v[4];
    #pragma unroll
    for (int nt = 0; nt < 4; ++nt) { b1v[nt] = b1p[nt * 16 + rl]; b2v[nt] = b2p[nt * 16 + rl]; }

    // staging map: thread -> (batch slb, sub-chunk su); each thread owns 12 float4 of a third
    const int slb = t / 36, su = t % 36;
    const float* zb = z + (size_t)(b0 + slb) * 5184;
    float4 pre[12];

#define ISSUE(P) do {                                                                  \
    const float* src_ = zb + (P) * 1728;                                               \
    _Pragma("unroll")                                                                  \
    for (int j = 0; j < 12; ++j) pre[j] = *(const float4*)(src_ + (j * 36 + su) * 4);  \
} while (0)

#define WRITEZ() do {                                                                  \
    _Pragma("unroll")                                                                  \
    for (int j = 0; j < 12; ++j) {                                                     \
        int f_ = (j * 36 + su) * 4;                                                    \
        int cell_ = f_ >> 6, d_ = f_ & 63;                                             \
        uint2 pk;                                                                      \
        pk.x = ((unsigned)f2bf(pre[j].y) << 16) | f2bf(pre[j].x);                      \
        pk.y = ((unsigned)f2bf(pre[j].w) << 16) | f2bf(pre[j].z);                      \
        *(uint2*)&lds[ZS + swz(cell_ * 16 + slb, d_)] = pk;                            \
    }                                                                                  \
} while (0)

    // col-wave persistent accumulators (static-indexed only)
    f32x4 cacc[3][4];
    #pragma unroll
    for (int tt = 0; tt < 3; ++tt)
        #pragma unroll
        for (int nt = 0; nt < 4; ++nt) cacc[tt][nt] = (f32x4)0.f;

    ISSUE(0);
    WRITEZ();
    __syncthreads();

    for (int p = 0; p < 3; ++p) {
        if (p < 2) ISSUE(p + 1);

        if (role == 0) {                 // ---- row MLP: grid row i = 3p+sub, full K ----
            f32x4 acc[4];
            #pragma unroll
            for (int nt = 0; nt < 4; ++nt) acc[nt] = (f32x4)0.f;
            #pragma unroll
            for (int kk = 0; kk < 18; ++kk) {
                const int cell = sub * 9 + (kk >> 1);
                const int f = (kk & 1) * 32 + kg * 8;
                short8 a = *(const short8*)&lds[ZS + swz(cell * 16 + rl, f)];
                #pragma unroll
                for (int nt = 0; nt < 4; ++nt) {
                    short8 bv = *(const short8*)(w1p + ((kk * 4 + nt) * 64 + lane) * 8);
                    acc[nt] = __builtin_amdgcn_mfma_f32_16x16x32_bf16(a, bv, acc[nt], 0, 0, 0);
                }
            }
            FLUSH(UPR, 3 * p + sub, acc);
        } else if (role == 1) {          // ---- box MLP: box (p, sub), full K ----
            f32x4 acc[4];
            #pragma unroll
            for (int nt = 0; nt < 4; ++nt) acc[nt] = (f32x4)0.f;
            #pragma unroll
            for (int s = 0; s < 9; ++s) {
                const int cell = (s / 3) * 9 + 3 * sub + (s % 3);
                #pragma unroll
                for (int h = 0; h < 2; ++h) {
                    const int kk = 2 * s + h;
                    const int f = h * 32 + kg * 8;
                    short8 a = *(const short8*)&lds[ZS + swz(cell * 16 + rl, f)];
                    #pragma unroll
                    for (int nt = 0; nt < 4; ++nt) {
                        short8 bv = *(const short8*)(w1p + ((kk * 4 + nt) * 64 + lane) * 8);
                        acc[nt] = __builtin_amdgcn_mfma_f32_16x16x32_bf16(a, bv, acc[nt], 0, 0, 0);
                    }
                }
            }
            FLUSH(UPB, 3 * p + sub, acc);
        } else {                         // ---- col MLP: cols {sub, sub+3, sub+6}, K-third ----
            #pragma unroll
            for (int tt = 0; tt < 3; ++tt) {
                const int j = sub + 3 * tt;
                #pragma unroll
                for (int q = 0; q < 6; ++q) {
                    const int kk = 6 * p + q;
                    const int cell = (q >> 1) * 9 + j;
                    const int f = (q & 1) * 32 + kg * 8;
                    short8 a = *(const short8*)&lds[ZS + swz(cell * 16 + rl, f)];
                    #pragma unroll
                    for (int nt = 0; nt < 4; ++nt) {
                        short8 bv = *(const short8*)(w1p + ((kk * 4 + nt) * 64 + lane) * 8);
                        cacc[tt][nt] = __builtin_amdgcn_mfma_f32_16x16x32_bf16(a, bv, cacc[tt][nt], 0, 0, 0);
                    }
                }
            }
            if (p == 2) {
                FLUSH(UPC, sub,     cacc[0]);
                FLUSH(UPC, sub + 3, cacc[1]);
                FLUSH(UPC, sub + 6, cacc[2]);
            }
        }
        __syncthreads();
        if (p < 2) { WRITEZ(); __syncthreads(); }
    }

    // ---- gate GEMM (K=192, box seg uses summed variant cg) + epilogue ----
    float gbv[4];
    #pragma unroll
    for (int nt = 0; nt < 4; ++nt) gbv[nt] = gb[nt * 16 + rl];
    const float alpha = alphap[0];
    const short* gwp = wsp + 122880;
    const int cg = w / 3, swg = w % 3;

    for (int pass = 0; pass < 3; ++pass) {
        const int tiles0 = swg * 9 + pass * 3;
        int rR[3], rC[3];
        #pragma unroll
        for (int tt = 0; tt < 3; ++tt) {
            int r = (tiles0 + tt) * 16 + rl;
            int lb = r / 27, j = r % 27;
            rR[tt] = lb * 9 + j / 3;
            rC[tt] = lb * 9 + cg + 3 * (j % 3);
        }
        f32x4 ag[3][4];
        #pragma unroll
        for (int tt = 0; tt < 3; ++tt)
            #pragma unroll
            for (int nt = 0; nt < 4; ++nt) ag[tt][nt] = (f32x4)0.f;

        #pragma unroll
        for (int s6 = 0; s6 < 6; ++s6) {
            const int kkp = (s6 < 4) ? s6 : 4 + 2 * cg + (s6 - 4);
            const int ko = (s6 & 1) * 32 + kg * 8;
            const int region = (s6 < 2) ? UPR : (s6 < 4) ? UPC : UPB;
            short8 a[3];
            #pragma unroll
            for (int tt = 0; tt < 3; ++tt) {
                int lr = (s6 >= 2 && s6 < 4) ? rC[tt] : rR[tt];
                a[tt] = *(const short8*)&lds[region + swz(lr, ko)];
            }
            #pragma unroll
            for (int nt = 0; nt < 4; ++nt) {
                short8 bv = *(const short8*)(gwp + ((kkp * 4 + nt) * 64 + lane) * 8);
                #pragma unroll
                for (int tt = 0; tt < 3; ++tt)
                    ag[tt][nt] = __builtin_amdgcn_mfma_f32_16x16x32_bf16(a[tt], bv, ag[tt][nt], 0, 0, 0);
            }
        }

        #pragma unroll
        for (int tt = 0; tt < 3; ++tt)
            #pragma unroll
            for (int reg = 0; reg < 4; ++reg) {
                int r = (tiles0 + tt) * 16 + kg * 4 + reg;
                int lb = r / 27, j = r % 27;
                int R = j / 3, C = cg + 3 * (j % 3);
                size_t zoff = (size_t)(b0 + lb) * 5184 + (size_t)(R * 9 + C) * 64;
                int rowR = lb * 9 + R, rowC = lb * 9 + C;
                #pragma unroll
                for (int nt = 0; nt < 4; ++nt) {
                    int d = nt * 16 + rl;
                    float g = sigmoidf(ag[tt][nt][reg] + gbv[nt]);
                    float du = bf2f(lds[UPR + swz(rowR, d)]);
                    float dc = bf2f(lds[UPC + swz(rowC, d)]);
                    float db = bf2f(lds[UPB + swz(rowR, (64 * cg + d) / 3)]);
                    float zv = z[zoff + d];
                    out[zoff + d] = zv + alpha * g * (du + dc + db);
                }
            }
    }
}

extern "C" void kernel_launch(void* const* d_in, const int* in_sizes, int n_in,
                              void* d_out, int out_size, void* d_ws, size_t ws_size,
                              hipStream_t stream) {
    const float* z   = (const float*)d_in[0];
    const float* w1r = (const float*)d_in[1];
    const float* b1r = (const float*)d_in[2];
    const float* w2r = (const float*)d_in[3];
    const float* b2r = (const float*)d_in[4];
    const float* w1c = (const float*)d_in[5];
    const float* b1c = (const float*)d_in[6];
    const float* w2c = (const float*)d_in[7];
    const float* b2c = (const float*)d_in[8];
    const float* w1b = (const float*)d_in[9];
    const float* b1b = (const float*)d_in[10];
    const float* w2b = (const float*)d_in[11];
    const float* b2b = (const float*)d_in[12];
    const float* gw  = (const float*)d_in[13];
    const float* gb  = (const float*)d_in[14];
    const float* al  = (const float*)d_in[15];
    float* outp = (float*)d_out;
    unsigned short* ws = (unsigned short*)d_ws;

    prepack_kernel<<<70, 256, 0, stream>>>(w1r, w1c, w1b, w2r, w2c, w2b, gw, ws);

    const int Btot = in_sizes[0] / 5184;    // 8192
    fisher_fused<<<Btot / 16, 576, 0, stream>>>(
        z, b1r, b2r, b1c, b2c, b1b, b2b, gb, al, (const short*)ws, outp);
}

// Round 5
// 470.503 us; speedup vs baseline: 1.5808x; 1.1975x over previous
//
#include <hip/hip_runtime.h>
#include <hip/hip_bf16.h>

typedef __attribute__((ext_vector_type(8))) short short8;
typedef __attribute__((ext_vector_type(4))) short short4v;
typedef __attribute__((ext_vector_type(4))) float f32x4;

__device__ __forceinline__ unsigned short f2bf(float f) {
    union { __hip_bfloat16 b; unsigned short u; } v;
    v.b = __float2bfloat16(f);
    return v.u;
}
__device__ __forceinline__ float bf2f(unsigned short u) {
    return __uint_as_float(((unsigned)u) << 16);
}
__device__ __forceinline__ float gelu_tanh(float x) {
    float u = 0.79788456080286536f * x * (1.0f + 0.044715f * x * x);
    return x * __builtin_amdgcn_rcpf(1.0f + __builtin_exp2f(-2.8853900817779268f * u));
}
__device__ __forceinline__ float sigmoidf(float x) {
    return __builtin_amdgcn_rcpf(1.0f + __builtin_exp2f(-1.4426950408889634f * x));
}
__device__ __forceinline__ int swz(int row, int col) {  // short-index swizzle
    return (row * 64 + col) ^ ((row & 7) << 3);
}

// ---------------- prepack: fp32 weights -> bf16 MFMA fragment layout in ws ----------------
// layout (shorts): W1[m] at m*36864 ; W2[m] at 110592+m*4096 ; GATE(320x64 eff.) at 122880
__global__ __launch_bounds__(256)
void prepack_kernel(const float* __restrict__ w1r, const float* __restrict__ w1c,
                    const float* __restrict__ w1b,
                    const float* __restrict__ w2r, const float* __restrict__ w2c,
                    const float* __restrict__ w2b,
                    const float* __restrict__ gw, unsigned short* __restrict__ ws)
{
    int t = blockIdx.x * 256 + threadIdx.x;
    if (t < 13824) {
        int wi = t / 4608, r = t % 4608;
        const float* src = (wi == 0) ? w1r : (wi == 1) ? w1c : w1b;
        unsigned short* dst = ws + wi * 36864;
        int lane = r & 63;
        int col = ((r >> 6) & 3) * 16 + (lane & 15);
        int k0 = (r >> 8) * 32 + (lane >> 4) * 8;
        #pragma unroll
        for (int j = 0; j < 8; ++j) dst[r * 8 + j] = f2bf(src[(k0 + j) * 64 + col]);
    } else if (t < 15360) {
        int q = t - 13824, wi = q / 512, r = q % 512;
        const float* src = (wi == 0) ? w2r : (wi == 1) ? w2c : w2b;
        unsigned short* dst = ws + 110592 + wi * 4096;
        int lane = r & 63;
        int col = ((r >> 6) & 3) * 16 + (lane & 15);
        int k0 = (r >> 8) * 32 + (lane >> 4) * 8;
        #pragma unroll
        for (int j = 0; j < 8; ++j) dst[r * 8 + j] = f2bf(src[(k0 + j) * 64 + col]);
    } else if (t < 17920) {
        int r = t - 15360;
        unsigned short* dst = ws + 122880;
        int lane = r & 63;
        int col = ((r >> 6) & 3) * 16 + (lane & 15);
        int k0 = (r >> 8) * 32 + (lane >> 4) * 8;
        #pragma unroll
        for (int j = 0; j < 8; ++j) {
            int krow = k0 + j;
            float v;
            if (krow < 128) {
                v = gw[krow * 64 + col];
            } else {
                int c = (krow - 128) >> 6, e = (krow - 128) & 63;
                int lo = 3 * e - 64 * c;
                v = 0.f;
                #pragma unroll
                for (int s = 0; s < 3; ++s) {
                    int dp = lo + s;
                    if (dp >= 0 && dp < 64) v += gw[(128 + dp) * 64 + col];
                }
            }
            dst[r * 8 + j] = f2bf(v);
        }
    }
}

// ================= Kernel 1: three MLPs, z staged once per third, UP -> ws =================
// ws UP layout (shorts, base UPWS_OFF): [(b*27 + slot)*64 + f], slot: 0-8 row i, 9-17 col j, 18-26 box j
#define UPWS_OFF 147456
#define ZS 0
#define HS 27648   // 9 waves * 1024 shorts ; LDS total 36864 shorts = 73728 B

// gelu+bias -> H -> W2 GEMM -> +b2 -> H -> coalesced global store to upws
#define FLUSH_G(SLOT, ACC) do {                                                               \
    asm volatile("s_waitcnt lgkmcnt(0)" ::: "memory");                                        \
    _Pragma("unroll")                                                                         \
    for (int nt = 0; nt < 4; ++nt) {                                                          \
        _Pragma("unroll")                                                                     \
        for (int reg = 0; reg < 4; ++reg)                                                     \
            lds[hoff + swz(kg * 4 + reg, nt * 16 + rl)] =                                     \
                f2bf(gelu_tanh(ACC[nt][reg] + b1v[nt]));                                      \
    }                                                                                         \
    asm volatile("s_waitcnt lgkmcnt(0)" ::: "memory");                                        \
    f32x4 a2c[4];                                                                             \
    _Pragma("unroll")                                                                         \
    for (int nt = 0; nt < 4; ++nt) a2c[nt] = (f32x4)0.f;                                      \
    _Pragma("unroll")                                                                         \
    for (int kk2 = 0; kk2 < 2; ++kk2) {                                                       \
        short8 a2 = *(const short8*)&lds[hoff + swz(rl, kk2 * 32 + kg * 8)];                  \
        _Pragma("unroll")                                                                     \
        for (int nt = 0; nt < 4; ++nt) {                                                      \
            short8 bw = *(const short8*)(w2p + ((kk2 * 4 + nt) * 64 + lane) * 8);             \
            a2c[nt] = __builtin_amdgcn_mfma_f32_16x16x32_bf16(a2, bw, a2c[nt], 0, 0, 0);      \
        }                                                                                     \
    }                                                                                         \
    asm volatile("s_waitcnt lgkmcnt(0)" ::: "memory");                                        \
    _Pragma("unroll")                                                                         \
    for (int nt = 0; nt < 4; ++nt) {                                                          \
        _Pragma("unroll")                                                                     \
        for (int reg = 0; reg < 4; ++reg)                                                     \
            lds[hoff + swz(kg * 4 + reg, nt * 16 + rl)] = f2bf(a2c[nt][reg] + b2v[nt]);       \
    }                                                                                         \
    asm volatile("s_waitcnt lgkmcnt(0)" ::: "memory");                                        \
    _Pragma("unroll")                                                                         \
    for (int p2 = 0; p2 < 2; ++p2) {                                                          \
        int lb_ = p2 * 8 + (lane >> 3), f0_ = (lane & 7) * 8;                                 \
        short8 v_ = *(const short8*)&lds[hoff + swz(lb_, f0_)];                               \
        *(short8*)(upws + ((size_t)(b0 + lb_) * 27 + (SLOT)) * 64 + f0_) = v_;                \
    }                                                                                         \
} while (0)

__global__ __launch_bounds__(576, 4)
void k1_mlp(const float* __restrict__ z,
            const float* __restrict__ b1r, const float* __restrict__ b2r,
            const float* __restrict__ b1c, const float* __restrict__ b2c,
            const float* __restrict__ b1b, const float* __restrict__ b2b,
            const short* __restrict__ wsp, unsigned short* __restrict__ upws)
{
    __shared__ __align__(16) unsigned short lds[36864];
    const int t = threadIdx.x;
    const int lane = t & 63;
    const int w = t >> 6;
    const int rl = lane & 15;
    const int kg = lane >> 4;
    const int b0 = blockIdx.x * 16;

    const int role = (w < 3) ? 0 : (w < 6) ? 1 : 2;   // 0=row 1=box 2=col
    const int sub  = (w < 3) ? w : (w < 6) ? w - 3 : w - 6;
    const int m    = (role == 0) ? 0 : (role == 1) ? 2 : 1;  // weight set: 0=row 1=col 2=box
    const int hoff = HS + w * 1024;

    const short* w1p = wsp + m * 36864;
    const short* w2p = wsp + 110592 + m * 4096;
    const float* b1p = (m == 0) ? b1r : (m == 1) ? b1c : b1b;
    const float* b2p = (m == 0) ? b2r : (m == 1) ? b2c : b2b;
    float b1v[4], b2v[4];
    #pragma unroll
    for (int nt = 0; nt < 4; ++nt) { b1v[nt] = b1p[nt * 16 + rl]; b2v[nt] = b2p[nt * 16 + rl]; }

    // staging map: thread -> (batch slb, chunk su); covers the 1728 floats of one third
    const int slb = t / 36, su = t % 36;
    const float* zb = z + (size_t)(b0 + slb) * 5184;

    // col-wave persistent accumulators (static indexing only)
    f32x4 cacc[3][4];
    #pragma unroll
    for (int tt = 0; tt < 3; ++tt)
        #pragma unroll
        for (int nt = 0; nt < 4; ++nt) cacc[tt][nt] = (f32x4)0.f;

    for (int p = 0; p < 3; ++p) {
        // ---- stage third p: 3 rounds of 4 float4 (transient regs, fenced) ----
        {
            const float* src = zb + p * 1728;
            #pragma unroll
            for (int rd = 0; rd < 3; ++rd) {
                float4 v[4];
                #pragma unroll
                for (int j2 = 0; j2 < 4; ++j2)
                    v[j2] = *(const float4*)(src + ((rd * 4 + j2) * 36 + su) * 4);
                #pragma unroll
                for (int j2 = 0; j2 < 4; ++j2) {
                    int f_ = ((rd * 4 + j2) * 36 + su) * 4;
                    int cl_ = f_ >> 6, d_ = f_ & 63;
                    uint2 pk;
                    pk.x = ((unsigned)f2bf(v[j2].y) << 16) | f2bf(v[j2].x);
                    pk.y = ((unsigned)f2bf(v[j2].w) << 16) | f2bf(v[j2].z);
                    *(uint2*)&lds[ZS + swz(cl_ * 16 + slb, d_)] = pk;
                }
                __builtin_amdgcn_sched_barrier(0);
            }
        }
        __syncthreads();

        // ---- compute on third p ----
        if (role == 0) {                 // row MLP: grid row 3p+sub, full K
            f32x4 acc[4];
            #pragma unroll
            for (int nt = 0; nt < 4; ++nt) acc[nt] = (f32x4)0.f;
            #pragma unroll
            for (int kk = 0; kk < 18; ++kk) {
                const int cell = sub * 9 + (kk >> 1);
                const int f = (kk & 1) * 32 + kg * 8;
                short8 a = *(const short8*)&lds[ZS + swz(cell * 16 + rl, f)];
                #pragma unroll
                for (int nt = 0; nt < 4; ++nt) {
                    short8 bv = *(const short8*)(w1p + ((kk * 4 + nt) * 64 + lane) * 8);
                    acc[nt] = __builtin_amdgcn_mfma_f32_16x16x32_bf16(a, bv, acc[nt], 0, 0, 0);
                }
            }
            FLUSH_G(3 * p + sub, acc);
        } else if (role == 1) {          // box MLP: box j = 3p+sub, full K
            f32x4 acc[4];
            #pragma unroll
            for (int nt = 0; nt < 4; ++nt) acc[nt] = (f32x4)0.f;
            #pragma unroll
            for (int s = 0; s < 9; ++s) {
                const int cell = (s / 3) * 9 + 3 * sub + (s % 3);
                #pragma unroll
                for (int h = 0; h < 2; ++h) {
                    const int kk = 2 * s + h;
                    const int f = h * 32 + kg * 8;
                    short8 a = *(const short8*)&lds[ZS + swz(cell * 16 + rl, f)];
                    #pragma unroll
                    for (int nt = 0; nt < 4; ++nt) {
                        short8 bv = *(const short8*)(w1p + ((kk * 4 + nt) * 64 + lane) * 8);
                        acc[nt] = __builtin_amdgcn_mfma_f32_16x16x32_bf16(a, bv, acc[nt], 0, 0, 0);
                    }
                }
            }
            FLUSH_G(18 + 3 * p + sub, acc);
        } else {                         // col MLP: cols {sub, sub+3, sub+6}, K-third accumulate
            #pragma unroll
            for (int tt = 0; tt < 3; ++tt) {
                const int j = sub + 3 * tt;
                #pragma unroll
                for (int q = 0; q < 6; ++q) {
                    const int kk = 6 * p + q;
                    const int cell = (q >> 1) * 9 + j;
                    const int f = (q & 1) * 32 + kg * 8;
                    short8 a = *(const short8*)&lds[ZS + swz(cell * 16 + rl, f)];
                    #pragma unroll
                    for (int nt = 0; nt < 4; ++nt) {
                        short8 bv = *(const short8*)(w1p + ((kk * 4 + nt) * 64 + lane) * 8);
                        cacc[tt][nt] = __builtin_amdgcn_mfma_f32_16x16x32_bf16(a, bv, cacc[tt][nt], 0, 0, 0);
                    }
                }
            }
            if (p == 2) {
                FLUSH_G(9 + sub,     cacc[0]);
                FLUSH_G(9 + sub + 3, cacc[1]);
                FLUSH_G(9 + sub + 6, cacc[2]);
            }
        }
        __syncthreads();
    }
}

// ================= Kernel 2: gate GEMM (swapped operands) + epilogue (round-3 verbatim) =================
__global__ __launch_bounds__(576, 4)
void k2_gate(const float* __restrict__ z, const unsigned short* __restrict__ upws,
             const short* __restrict__ wsp, const float* __restrict__ gb,
             const float* __restrict__ alphap, float* __restrict__ out)
{
    __shared__ __align__(16) unsigned short ups[27648];  // [b*27 + slot][64] swizzled
    __shared__ __align__(16) unsigned short tscr[9][1024];
    const int t = threadIdx.x;
    const int lane = t & 63;
    const int w = t >> 6;
    const int rl = lane & 15;
    const int kg = lane >> 4;
    const int b0 = blockIdx.x * 16;

    #pragma unroll
    for (int c6 = 0; c6 < 6; ++c6) {
        int chunk = t + c6 * 576;
        int row = chunk >> 3, f0 = (chunk & 7) * 8;
        short8 v = *(const short8*)(upws + (size_t)b0 * 1728 + chunk * 8);
        *(short8*)&ups[swz(row, f0)] = v;
    }
    __syncthreads();

    const short* gwp = wsp + 122880;
    const float alpha = alphap[0];
    float gbl[4][4];
    #pragma unroll
    for (int mt = 0; mt < 4; ++mt)
        #pragma unroll
        for (int reg = 0; reg < 4; ++reg) gbl[mt][reg] = gb[mt * 16 + kg * 4 + reg];

    const int c = w % 3, wg = w / 3;

    #pragma unroll
    for (int tl = 0; tl < 9; ++tl) {
        int e = (wg * 9 + tl) * 16 + rl;
        int b = e / 27, rem = e % 27, R = rem / 3, q = rem % 3, C = c + 3 * q;
        int rowR = b * 27 + R, rowC = b * 27 + 9 + C, rowB = b * 27 + 18 + R;

        f32x4 acc[4];
        #pragma unroll
        for (int mt = 0; mt < 4; ++mt) acc[mt] = (f32x4)0.f;

        #pragma unroll
        for (int s6 = 0; s6 < 6; ++s6) {
            int seg = s6 >> 1;
            int kkp = (s6 < 4) ? s6 : 4 + 2 * c + (s6 - 4);
            int row = (seg == 0) ? rowR : (seg == 1) ? rowC : rowB;
            int f = (s6 & 1) * 32 + kg * 8;
            short8 bfrag = *(const short8*)&ups[swz(row, f)];
            #pragma unroll
            for (int mt = 0; mt < 4; ++mt) {
                short8 afrag = *(const short8*)(gwp + ((kkp * 4 + mt) * 64 + lane) * 8);
                acc[mt] = __builtin_amdgcn_mfma_f32_16x16x32_bf16(afrag, bfrag, acc[mt], 0, 0, 0);
            }
        }

        #pragma unroll
        for (int mt = 0; mt < 4; ++mt) {
            short4v du4 = *(const short4v*)&ups[swz(rowR, mt * 16 + kg * 4)];
            short4v dc4 = *(const short4v*)&ups[swz(rowC, mt * 16 + kg * 4)];
            #pragma unroll
            for (int reg = 0; reg < 4; ++reg) {
                int fidx = mt * 16 + kg * 4 + reg;
                float g = sigmoidf(acc[mt][reg] + gbl[mt][reg]);
                float duv = bf2f((unsigned short)du4[reg]);
                float dcv = bf2f((unsigned short)dc4[reg]);
                float dbv = bf2f(ups[swz(rowB, (64 * c + fidx) / 3)]);
                tscr[w][swz(rl, fidx)] = f2bf(alpha * g * (duv + dcv + dbv));
            }
        }
        asm volatile("s_waitcnt lgkmcnt(0)" ::: "memory");
        #pragma unroll
        for (int p = 0; p < 2; ++p) {
            int cl = p * 8 + (lane >> 3), f0 = (lane & 7) * 8;
            int e2 = (wg * 9 + tl) * 16 + cl;
            int b2 = e2 / 27, rem2 = e2 % 27, R2 = rem2 / 3, C2 = c + 3 * (rem2 % 3);
            short8 tv = *(const short8*)&tscr[w][swz(cl, f0)];
            const float* zp = z + (size_t)(b0 + b2) * 5184 + (size_t)(R2 * 9 + C2) * 64 + f0;
            float4 z0 = *(const float4*)zp;
            float4 z1 = *(const float4*)(zp + 4);
            float4 o0, o1;
            o0.x = z0.x + bf2f((unsigned short)tv[0]);
            o0.y = z0.y + bf2f((unsigned short)tv[1]);
            o0.z = z0.z + bf2f((unsigned short)tv[2]);
            o0.w = z0.w + bf2f((unsigned short)tv[3]);
            o1.x = z1.x + bf2f((unsigned short)tv[4]);
            o1.y = z1.y + bf2f((unsigned short)tv[5]);
            o1.z = z1.z + bf2f((unsigned short)tv[6]);
            o1.w = z1.w + bf2f((unsigned short)tv[7]);
            float* op = out + (size_t)(b0 + b2) * 5184 + (size_t)(R2 * 9 + C2) * 64 + f0;
            *(float4*)op = o0;
            *(float4*)(op + 4) = o1;
        }
        asm volatile("s_waitcnt lgkmcnt(0)" ::: "memory");
    }
}

extern "C" void kernel_launch(void* const* d_in, const int* in_sizes, int n_in,
                              void* d_out, int out_size, void* d_ws, size_t ws_size,
                              hipStream_t stream) {
    const float* z   = (const float*)d_in[0];
    const float* w1r = (const float*)d_in[1];
    const float* b1r = (const float*)d_in[2];
    const float* w2r = (const float*)d_in[3];
    const float* b2r = (const float*)d_in[4];
    const float* w1c = (const float*)d_in[5];
    const float* b1c = (const float*)d_in[6];
    const float* w2c = (const float*)d_in[7];
    const float* b2c = (const float*)d_in[8];
    const float* w1b = (const float*)d_in[9];
    const float* b1b = (const float*)d_in[10];
    const float* w2b = (const float*)d_in[11];
    const float* b2b = (const float*)d_in[12];
    const float* gw  = (const float*)d_in[13];
    const float* gb  = (const float*)d_in[14];
    const float* al  = (const float*)d_in[15];
    float* outp = (float*)d_out;
    unsigned short* ws = (unsigned short*)d_ws;

    prepack_kernel<<<70, 256, 0, stream>>>(w1r, w1c, w1b, w2r, w2c, w2b, gw, ws);

    const int Btot = in_sizes[0] / 5184;    // 8192
    unsigned short* upws = ws + UPWS_OFF;
    k1_mlp<<<Btot / 16, 576, 0, stream>>>(z, b1r, b2r, b1c, b2c, b1b, b2b,
                                          (const short*)ws, upws);
    k2_gate<<<Btot / 16, 576, 0, stream>>>(z, upws, (const short*)ws, gb, al, outp);
}

// Round 6
// 449.976 us; speedup vs baseline: 1.6530x; 1.0456x over previous
//
#include <hip/hip_runtime.h>
#include <hip/hip_bf16.h>

typedef __attribute__((ext_vector_type(8))) short short8;
typedef __attribute__((ext_vector_type(4))) short short4v;
typedef __attribute__((ext_vector_type(4))) float f32x4;

__device__ __forceinline__ unsigned short f2bf(float f) {
    union { __hip_bfloat16 b; unsigned short u; } v;
    v.b = __float2bfloat16(f);
    return v.u;
}
__device__ __forceinline__ float bf2f(unsigned short u) {
    return __uint_as_float(((unsigned)u) << 16);
}
__device__ __forceinline__ float gelu_tanh(float x) {
    float u = 0.79788456080286536f * x * (1.0f + 0.044715f * x * x);
    return x * __builtin_amdgcn_rcpf(1.0f + __builtin_exp2f(-2.8853900817779268f * u));
}
__device__ __forceinline__ float sigmoidf(float x) {
    return __builtin_amdgcn_rcpf(1.0f + __builtin_exp2f(-1.4426950408889634f * x));
}
__device__ __forceinline__ int swz(int row, int col) {  // short-index swizzle
    return (row * 64 + col) ^ ((row & 7) << 3);
}

// ---------------- prepack: fp32 weights -> bf16 MFMA fragment layout in ws ----------------
// layout (shorts): W1[m] at m*36864 ; W2[m] at 110592+m*4096 ; GATE(320x64 eff.) at 122880
__global__ __launch_bounds__(256)
void prepack_kernel(const float* __restrict__ w1r, const float* __restrict__ w1c,
                    const float* __restrict__ w1b,
                    const float* __restrict__ w2r, const float* __restrict__ w2c,
                    const float* __restrict__ w2b,
                    const float* __restrict__ gw, unsigned short* __restrict__ ws)
{
    int t = blockIdx.x * 256 + threadIdx.x;
    if (t < 13824) {
        int wi = t / 4608, r = t % 4608;
        const float* src = (wi == 0) ? w1r : (wi == 1) ? w1c : w1b;
        unsigned short* dst = ws + wi * 36864;
        int lane = r & 63;
        int col = ((r >> 6) & 3) * 16 + (lane & 15);
        int k0 = (r >> 8) * 32 + (lane >> 4) * 8;
        #pragma unroll
        for (int j = 0; j < 8; ++j) dst[r * 8 + j] = f2bf(src[(k0 + j) * 64 + col]);
    } else if (t < 15360) {
        int q = t - 13824, wi = q / 512, r = q % 512;
        const float* src = (wi == 0) ? w2r : (wi == 1) ? w2c : w2b;
        unsigned short* dst = ws + 110592 + wi * 4096;
        int lane = r & 63;
        int col = ((r >> 6) & 3) * 16 + (lane & 15);
        int k0 = (r >> 8) * 32 + (lane >> 4) * 8;
        #pragma unroll
        for (int j = 0; j < 8; ++j) dst[r * 8 + j] = f2bf(src[(k0 + j) * 64 + col]);
    } else if (t < 17920) {
        int r = t - 15360;
        unsigned short* dst = ws + 122880;
        int lane = r & 63;
        int col = ((r >> 6) & 3) * 16 + (lane & 15);
        int k0 = (r >> 8) * 32 + (lane >> 4) * 8;
        #pragma unroll
        for (int j = 0; j < 8; ++j) {
            int krow = k0 + j;
            float v;
            if (krow < 128) {
                v = gw[krow * 64 + col];
            } else {
                int c = (krow - 128) >> 6, e = (krow - 128) & 63;
                int lo = 3 * e - 64 * c;
                v = 0.f;
                #pragma unroll
                for (int s = 0; s < 3; ++s) {
                    int dp = lo + s;
                    if (dp >= 0 && dp < 64) v += gw[(128 + dp) * 64 + col];
                }
            }
            dst[r * 8 + j] = f2bf(v);
        }
    }
}

// ================= Kernel 1: 27 independent strided GEMMs, no barriers, no staging =================
// ws UP layout (shorts, base UPWS_OFF): [(b*27 + slot)*64 + f], slot: 0-8 row i, 9-17 col j, 18-26 box j
#define UPWS_OFF 147456

// gelu+bias -> H -> W2 GEMM -> +b2 -> H -> coalesced global store to upws (validated r3/r5)
#define FLUSH_G(SLOT, ACC) do {                                                               \
    asm volatile("s_waitcnt lgkmcnt(0)" ::: "memory");                                        \
    _Pragma("unroll")                                                                         \
    for (int nt = 0; nt < 4; ++nt) {                                                          \
        _Pragma("unroll")                                                                     \
        for (int reg = 0; reg < 4; ++reg)                                                     \
            hlds[hoff + swz(kg * 4 + reg, nt * 16 + rl)] =                                    \
                f2bf(gelu_tanh(ACC[nt][reg] + b1v[nt]));                                      \
    }                                                                                         \
    asm volatile("s_waitcnt lgkmcnt(0)" ::: "memory");                                        \
    f32x4 a2c[4];                                                                             \
    _Pragma("unroll")                                                                         \
    for (int nt = 0; nt < 4; ++nt) a2c[nt] = (f32x4)0.f;                                      \
    _Pragma("unroll")                                                                         \
    for (int kk2 = 0; kk2 < 2; ++kk2) {                                                       \
        short8 a2 = *(const short8*)&hlds[hoff + swz(rl, kk2 * 32 + kg * 8)];                 \
        _Pragma("unroll")                                                                     \
        for (int nt = 0; nt < 4; ++nt) {                                                      \
            short8 bw = *(const short8*)(w2p + ((kk2 * 4 + nt) * 64 + lane) * 8);             \
            a2c[nt] = __builtin_amdgcn_mfma_f32_16x16x32_bf16(a2, bw, a2c[nt], 0, 0, 0);      \
        }                                                                                     \
    }                                                                                         \
    asm volatile("s_waitcnt lgkmcnt(0)" ::: "memory");                                        \
    _Pragma("unroll")                                                                         \
    for (int nt = 0; nt < 4; ++nt) {                                                          \
        _Pragma("unroll")                                                                     \
        for (int reg = 0; reg < 4; ++reg)                                                     \
            hlds[hoff + swz(kg * 4 + reg, nt * 16 + rl)] = f2bf(a2c[nt][reg] + b2v[nt]);      \
    }                                                                                         \
    asm volatile("s_waitcnt lgkmcnt(0)" ::: "memory");                                        \
    _Pragma("unroll")                                                                         \
    for (int p2 = 0; p2 < 2; ++p2) {                                                          \
        int lb_ = p2 * 8 + (lane >> 3), f0_ = (lane & 7) * 8;                                 \
        short8 v_ = *(const short8*)&hlds[hoff + swz(lb_, f0_)];                              \
        *(short8*)(upws + ((size_t)(b0 + lb_) * 27 + (SLOT)) * 64 + f0_) = v_;                \
    }                                                                                         \
} while (0)

__global__ __launch_bounds__(576, 2)
void k1_mlp(const float* __restrict__ z,
            const float* __restrict__ b1r, const float* __restrict__ b2r,
            const float* __restrict__ b1c, const float* __restrict__ b2c,
            const float* __restrict__ b1b, const float* __restrict__ b2b,
            const short* __restrict__ wsp, unsigned short* __restrict__ upws)
{
    __shared__ __align__(16) unsigned short hlds[9216];   // 9 waves x 16x64 scratch, 18 KB
    const int t = threadIdx.x;
    const int lane = t & 63;
    const int w = t >> 6;          // 0..8
    const int rl = lane & 15;      // batch within tile (A-row)
    const int kg = lane >> 4;      // k-group
    const int b0 = blockIdx.x * 16;
    const int hoff = w * 1024;

    const int type = w / 3;        // 0=row 1=col 2=box
    const int sub  = w % 3;        // slot group within type

    const short* w1p = wsp + type * 36864;
    const short* w2p = wsp + 110592 + type * 4096;
    const float* b1p = (type == 0) ? b1r : (type == 1) ? b1c : b1b;
    const float* b2p = (type == 0) ? b2r : (type == 1) ? b2c : b2b;
    float b1v[4], b2v[4];
    #pragma unroll
    for (int nt = 0; nt < 4; ++nt) { b1v[nt] = b1p[nt * 16 + rl]; b2v[nt] = b2p[nt * 16 + rl]; }

    // per-lane base: batch b0+rl, k-subgroup kg
    const float* zrow = z + (size_t)(b0 + rl) * 5184 + kg * 8;

    for (int sl = 0; sl < 3; ++sl) {
        const int j = sub * 3 + sl;
        // wave-uniform slot base offset into the 5184-float z row
        const int cj = (type == 0) ? j * 576
                     : (type == 1) ? j * 64
                     :               (j / 3) * 1728 + (j % 3) * 192;

        f32x4 acc[4];
        #pragma unroll
        for (int nt = 0; nt < 4; ++nt) acc[nt] = (f32x4)0.f;

        #pragma unroll
        for (int kk = 0; kk < 18; ++kk) {
            const int s = kk >> 1, half = kk & 1;
            const int soff = (type == 0) ? s * 64
                           : (type == 1) ? s * 576
                           :               (s / 3) * 576 + (s % 3) * 64;
            const float* ap = zrow + cj + soff + half * 32;
            float4 f0 = *(const float4*)ap;
            float4 f1 = *(const float4*)(ap + 4);
            short8 a;
            a[0] = (short)f2bf(f0.x); a[1] = (short)f2bf(f0.y);
            a[2] = (short)f2bf(f0.z); a[3] = (short)f2bf(f0.w);
            a[4] = (short)f2bf(f1.x); a[5] = (short)f2bf(f1.y);
            a[6] = (short)f2bf(f1.z); a[7] = (short)f2bf(f1.w);
            #pragma unroll
            for (int nt = 0; nt < 4; ++nt) {
                short8 bv = *(const short8*)(w1p + ((kk * 4 + nt) * 64 + lane) * 8);
                acc[nt] = __builtin_amdgcn_mfma_f32_16x16x32_bf16(a, bv, acc[nt], 0, 0, 0);
            }
        }
        FLUSH_G(type * 9 + j, acc);
    }
}

// ================= Kernel 2: gate GEMM (swapped operands) + epilogue (round-3 verbatim) =================
__global__ __launch_bounds__(576, 4)
void k2_gate(const float* __restrict__ z, const unsigned short* __restrict__ upws,
             const short* __restrict__ wsp, const float* __restrict__ gb,
             const float* __restrict__ alphap, float* __restrict__ out)
{
    __shared__ __align__(16) unsigned short ups[27648];  // [b*27 + slot][64] swizzled
    __shared__ __align__(16) unsigned short tscr[9][1024];
    const int t = threadIdx.x;
    const int lane = t & 63;
    const int w = t >> 6;
    const int rl = lane & 15;
    const int kg = lane >> 4;
    const int b0 = blockIdx.x * 16;

    #pragma unroll
    for (int c6 = 0; c6 < 6; ++c6) {
        int chunk = t + c6 * 576;
        int row = chunk >> 3, f0 = (chunk & 7) * 8;
        short8 v = *(const short8*)(upws + (size_t)b0 * 1728 + chunk * 8);
        *(short8*)&ups[swz(row, f0)] = v;
    }
    __syncthreads();

    const short* gwp = wsp + 122880;
    const float alpha = alphap[0];
    float gbl[4][4];
    #pragma unroll
    for (int mt = 0; mt < 4; ++mt)
        #pragma unroll
        for (int reg = 0; reg < 4; ++reg) gbl[mt][reg] = gb[mt * 16 + kg * 4 + reg];

    const int c = w % 3, wg = w / 3;

    #pragma unroll
    for (int tl = 0; tl < 9; ++tl) {
        int e = (wg * 9 + tl) * 16 + rl;
        int b = e / 27, rem = e % 27, R = rem / 3, q = rem % 3, C = c + 3 * q;
        int rowR = b * 27 + R, rowC = b * 27 + 9 + C, rowB = b * 27 + 18 + R;

        f32x4 acc[4];
        #pragma unroll
        for (int mt = 0; mt < 4; ++mt) acc[mt] = (f32x4)0.f;

        #pragma unroll
        for (int s6 = 0; s6 < 6; ++s6) {
            int seg = s6 >> 1;
            int kkp = (s6 < 4) ? s6 : 4 + 2 * c + (s6 - 4);
            int row = (seg == 0) ? rowR : (seg == 1) ? rowC : rowB;
            int f = (s6 & 1) * 32 + kg * 8;
            short8 bfrag = *(const short8*)&ups[swz(row, f)];
            #pragma unroll
            for (int mt = 0; mt < 4; ++mt) {
                short8 afrag = *(const short8*)(gwp + ((kkp * 4 + mt) * 64 + lane) * 8);
                acc[mt] = __builtin_amdgcn_mfma_f32_16x16x32_bf16(afrag, bfrag, acc[mt], 0, 0, 0);
            }
        }

        #pragma unroll
        for (int mt = 0; mt < 4; ++mt) {
            short4v du4 = *(const short4v*)&ups[swz(rowR, mt * 16 + kg * 4)];
            short4v dc4 = *(const short4v*)&ups[swz(rowC, mt * 16 + kg * 4)];
            #pragma unroll
            for (int reg = 0; reg < 4; ++reg) {
                int fidx = mt * 16 + kg * 4 + reg;
                float g = sigmoidf(acc[mt][reg] + gbl[mt][reg]);
                float duv = bf2f((unsigned short)du4[reg]);
                float dcv = bf2f((unsigned short)dc4[reg]);
                float dbv = bf2f(ups[swz(rowB, (64 * c + fidx) / 3)]);
                tscr[w][swz(rl, fidx)] = f2bf(alpha * g * (duv + dcv + dbv));
            }
        }
        asm volatile("s_waitcnt lgkmcnt(0)" ::: "memory");
        #pragma unroll
        for (int p = 0; p < 2; ++p) {
            int cl = p * 8 + (lane >> 3), f0 = (lane & 7) * 8;
            int e2 = (wg * 9 + tl) * 16 + cl;
            int b2 = e2 / 27, rem2 = e2 % 27, R2 = rem2 / 3, C2 = c + 3 * (rem2 % 3);
            short8 tv = *(const short8*)&tscr[w][swz(cl, f0)];
            const float* zp = z + (size_t)(b0 + b2) * 5184 + (size_t)(R2 * 9 + C2) * 64 + f0;
            float4 z0 = *(const float4*)zp;
            float4 z1 = *(const float4*)(zp + 4);
            float4 o0, o1;
            o0.x = z0.x + bf2f((unsigned short)tv[0]);
            o0.y = z0.y + bf2f((unsigned short)tv[1]);
            o0.z = z0.z + bf2f((unsigned short)tv[2]);
            o0.w = z0.w + bf2f((unsigned short)tv[3]);
            o1.x = z1.x + bf2f((unsigned short)tv[4]);
            o1.y = z1.y + bf2f((unsigned short)tv[5]);
            o1.z = z1.z + bf2f((unsigned short)tv[6]);
            o1.w = z1.w + bf2f((unsigned short)tv[7]);
            float* op = out + (size_t)(b0 + b2) * 5184 + (size_t)(R2 * 9 + C2) * 64 + f0;
            *(float4*)op = o0;
            *(float4*)(op + 4) = o1;
        }
        asm volatile("s_waitcnt lgkmcnt(0)" ::: "memory");
    }
}

extern "C" void kernel_launch(void* const* d_in, const int* in_sizes, int n_in,
                              void* d_out, int out_size, void* d_ws, size_t ws_size,
                              hipStream_t stream) {
    const float* z   = (const float*)d_in[0];
    const float* w1r = (const float*)d_in[1];
    const float* b1r = (const float*)d_in[2];
    const float* w2r = (const float*)d_in[3];
    const float* b2r = (const float*)d_in[4];
    const float* w1c = (const float*)d_in[5];
    const float* b1c = (const float*)d_in[6];
    const float* w2c = (const float*)d_in[7];
    const float* b2c = (const float*)d_in[8];
    const float* w1b = (const float*)d_in[9];
    const float* b1b = (const float*)d_in[10];
    const float* w2b = (const float*)d_in[11];
    const float* b2b = (const float*)d_in[12];
    const float* gw  = (const float*)d_in[13];
    const float* gb  = (const float*)d_in[14];
    const float* al  = (const float*)d_in[15];
    float* outp = (float*)d_out;
    unsigned short* ws = (unsigned short*)d_ws;

    prepack_kernel<<<70, 256, 0, stream>>>(w1r, w1c, w1b, w2r, w2c, w2b, gw, ws);

    const int Btot = in_sizes[0] / 5184;    // 8192
    unsigned short* upws = ws + UPWS_OFF;
    k1_mlp<<<Btot / 16, 576, 0, stream>>>(z, b1r, b2r, b1c, b2c, b1b, b2b,
                                          (const short*)ws, upws);
    k2_gate<<<Btot / 16, 576, 0, stream>>>(z, upws, (const short*)ws, gb, al, outp);
}

// Round 7
// 188.766 us; speedup vs baseline: 3.9403x; 2.3838x over previous
//
#include <hip/hip_runtime.h>
#include <hip/hip_bf16.h>

typedef __attribute__((ext_vector_type(8))) short short8;
typedef __attribute__((ext_vector_type(4))) short short4v;
typedef __attribute__((ext_vector_type(4))) float f32x4;

__device__ __forceinline__ unsigned short f2bf(float f) {
    union { __hip_bfloat16 b; unsigned short u; } v;
    v.b = __float2bfloat16(f);
    return v.u;
}
__device__ __forceinline__ float bf2f(unsigned short u) {
    return __uint_as_float(((unsigned)u) << 16);
}
__device__ __forceinline__ float gelu_tanh(float x) {
    float u = 0.79788456080286536f * x * (1.0f + 0.044715f * x * x);
    return x * __builtin_amdgcn_rcpf(1.0f + __builtin_exp2f(-2.8853900817779268f * u));
}
__device__ __forceinline__ float sigmoidf(float x) {
    return __builtin_amdgcn_rcpf(1.0f + __builtin_exp2f(-1.4426950408889634f * x));
}
__device__ __forceinline__ int swz(int row, int col) {  // short-index swizzle
    return (row * 64 + col) ^ ((row & 7) << 3);
}

// ---------------- prepack: fp32 weights -> bf16 MFMA fragment layout in ws ----------------
// layout (shorts): W1[m] at m*36864 ; W2[m] at 110592+m*4096 ; GATE(320x64 eff.) at 122880
__global__ __launch_bounds__(256)
void prepack_kernel(const float* __restrict__ w1r, const float* __restrict__ w1c,
                    const float* __restrict__ w1b,
                    const float* __restrict__ w2r, const float* __restrict__ w2c,
                    const float* __restrict__ w2b,
                    const float* __restrict__ gw, unsigned short* __restrict__ ws)
{
    int t = blockIdx.x * 256 + threadIdx.x;
    if (t < 13824) {
        int wi = t / 4608, r = t % 4608;
        const float* src = (wi == 0) ? w1r : (wi == 1) ? w1c : w1b;
        unsigned short* dst = ws + wi * 36864;
        int lane = r & 63;
        int col = ((r >> 6) & 3) * 16 + (lane & 15);
        int k0 = (r >> 8) * 32 + (lane >> 4) * 8;
        #pragma unroll
        for (int j = 0; j < 8; ++j) dst[r * 8 + j] = f2bf(src[(k0 + j) * 64 + col]);
    } else if (t < 15360) {
        int q = t - 13824, wi = q / 512, r = q % 512;
        const float* src = (wi == 0) ? w2r : (wi == 1) ? w2c : w2b;
        unsigned short* dst = ws + 110592 + wi * 4096;
        int lane = r & 63;
        int col = ((r >> 6) & 3) * 16 + (lane & 15);
        int k0 = (r >> 8) * 32 + (lane >> 4) * 8;
        #pragma unroll
        for (int j = 0; j < 8; ++j) dst[r * 8 + j] = f2bf(src[(k0 + j) * 64 + col]);
    } else if (t < 17920) {
        int r = t - 15360;
        unsigned short* dst = ws + 122880;
        int lane = r & 63;
        int col = ((r >> 6) & 3) * 16 + (lane & 15);
        int k0 = (r >> 8) * 32 + (lane >> 4) * 8;
        #pragma unroll
        for (int j = 0; j < 8; ++j) {
            int krow = k0 + j;
            float v;
            if (krow < 128) {
                v = gw[krow * 64 + col];
            } else {
                int c = (krow - 128) >> 6, e = (krow - 128) & 63;
                int lo = 3 * e - 64 * c;
                v = 0.f;
                #pragma unroll
                for (int s = 0; s < 3; ++s) {
                    int dp = lo + s;
                    if (dp >= 0 && dp < 64) v += gw[(128 + dp) * 64 + col];
                }
            }
            dst[r * 8 + j] = f2bf(v);
        }
    }
}

// ================= Kernel 1: stage 8 batches of z coalesced -> LDS, 15 slot-tiles, no persistent state =================
// ws UP layout (shorts, base UPWS_OFF): [(b*27 + slot)*64 + f], slot: 0-8 row, 9-17 col, 18-26 box
#define UPWS_OFF 147456

__global__ __launch_bounds__(512, 2)
void k1_mlp(const float* __restrict__ z,
            const float* __restrict__ b1r, const float* __restrict__ b2r,
            const float* __restrict__ b1c, const float* __restrict__ b2c,
            const float* __restrict__ b1b, const float* __restrict__ b2b,
            const short* __restrict__ wsp, unsigned short* __restrict__ upws)
{
    __shared__ __align__(16) unsigned short zl[41472];   // 8 b x 81 cells x 64 f, swizzled (83 KB)
    __shared__ __align__(16) unsigned short hlds[8192];  // 8 waves x 16x64 scratch (16 KB)
    const int t = threadIdx.x;
    const int lane = t & 63;
    const int w = t >> 6;          // 0..7
    const int rl = lane & 15;
    const int kg = lane >> 4;
    const int b0 = blockIdx.x * 8;
    const int hoff = w * 1024;

    // ---- stage: 8*5184 floats, perfectly coalesced stream, inline f32->bf16 ----
    {
        const float* src = z + (size_t)b0 * 5184;
        for (int g = t; g < 10368; g += 512) {
            float4 v = *(const float4*)(src + g * 4);
            int row = g >> 4;           // b*81 + cell
            int col = (g & 15) * 4;
            uint2 pk;
            pk.x = ((unsigned)f2bf(v.y) << 16) | f2bf(v.x);
            pk.y = ((unsigned)f2bf(v.w) << 16) | f2bf(v.z);
            *(uint2*)&zl[swz(row, col)] = pk;
        }
    }
    __syncthreads();

    // ---- 15 tiles: tile = type*5 + pr ; rows = 8 batches x slots {2pr, 2pr+1} ----
    for (int tt = w; tt < 15; tt += 8) {
        const int type = tt / 5, pr = tt % 5;
        const int j0 = 2 * pr, j1 = 2 * pr + 1;
        const int has1 = (j1 < 9);
        const int member = rl >> 3, b = rl & 7;
        const int j = (member && has1) ? j1 : j0;
        const int rowbase = b * 81 + ((type == 0) ? j * 9
                                     : (type == 1) ? j
                                     :               (j / 3) * 27 + (j % 3) * 3);

        const short* w1p = wsp + type * 36864;
        const short* w2p = wsp + 110592 + type * 4096;
        const float* b1p = (type == 0) ? b1r : (type == 1) ? b1c : b1b;
        const float* b2p = (type == 0) ? b2r : (type == 1) ? b2c : b2b;
        float b1v[4], b2v[4];
        #pragma unroll
        for (int nt = 0; nt < 4; ++nt) { b1v[nt] = b1p[nt * 16 + rl]; b2v[nt] = b2p[nt * 16 + rl]; }

        f32x4 acc[4];
        #pragma unroll
        for (int nt = 0; nt < 4; ++nt) acc[nt] = (f32x4)0.f;

        #pragma unroll
        for (int kk = 0; kk < 18; ++kk) {
            const int s = kk >> 1;
            const int sadd = (type == 0) ? s : (type == 1) ? 9 * s : (s / 3) * 9 + (s % 3);
            const int feat = (kk & 1) * 32 + kg * 8;
            short8 a = *(const short8*)&zl[swz(rowbase + sadd, feat)];
            #pragma unroll
            for (int nt = 0; nt < 4; ++nt) {
                short8 bv = *(const short8*)(w1p + ((kk * 4 + nt) * 64 + lane) * 8);
                acc[nt] = __builtin_amdgcn_mfma_f32_16x16x32_bf16(a, bv, acc[nt], 0, 0, 0);
            }
        }

        // ---- flush: gelu -> H -> W2 -> +b2 -> H -> coalesced UP stores (validated path) ----
        asm volatile("s_waitcnt lgkmcnt(0)" ::: "memory");   // WAR vs prev tile's hlds reads
        #pragma unroll
        for (int nt = 0; nt < 4; ++nt)
            #pragma unroll
            for (int reg = 0; reg < 4; ++reg)
                hlds[hoff + swz(kg * 4 + reg, nt * 16 + rl)] =
                    f2bf(gelu_tanh(acc[nt][reg] + b1v[nt]));
        asm volatile("s_waitcnt lgkmcnt(0)" ::: "memory");

        f32x4 a2c[4];
        #pragma unroll
        for (int nt = 0; nt < 4; ++nt) a2c[nt] = (f32x4)0.f;
        #pragma unroll
        for (int kk2 = 0; kk2 < 2; ++kk2) {
            short8 a2 = *(const short8*)&hlds[hoff + swz(rl, kk2 * 32 + kg * 8)];
            #pragma unroll
            for (int nt = 0; nt < 4; ++nt) {
                short8 bw = *(const short8*)(w2p + ((kk2 * 4 + nt) * 64 + lane) * 8);
                a2c[nt] = __builtin_amdgcn_mfma_f32_16x16x32_bf16(a2, bw, a2c[nt], 0, 0, 0);
            }
        }
        asm volatile("s_waitcnt lgkmcnt(0)" ::: "memory");
        #pragma unroll
        for (int nt = 0; nt < 4; ++nt)
            #pragma unroll
            for (int reg = 0; reg < 4; ++reg)
                hlds[hoff + swz(kg * 4 + reg, nt * 16 + rl)] = f2bf(a2c[nt][reg] + b2v[nt]);
        asm volatile("s_waitcnt lgkmcnt(0)" ::: "memory");

        #pragma unroll
        for (int p2 = 0; p2 < 2; ++p2) {
            if (p2 == 1 && !has1) break;
            const int hrow = p2 * 8 + (lane >> 3), f0 = (lane & 7) * 8;
            const int slot = type * 9 + (p2 ? j1 : j0);
            short8 v = *(const short8*)&hlds[hoff + swz(hrow, f0)];
            *(short8*)(upws + ((size_t)(b0 + (hrow & 7)) * 27 + slot) * 64 + f0) = v;
        }
    }
}

// ================= Kernel 2: gate GEMM (swapped operands) + epilogue (round-3 verbatim) =================
__global__ __launch_bounds__(576, 4)
void k2_gate(const float* __restrict__ z, const unsigned short* __restrict__ upws,
             const short* __restrict__ wsp, const float* __restrict__ gb,
             const float* __restrict__ alphap, float* __restrict__ out)
{
    __shared__ __align__(16) unsigned short ups[27648];  // [b*27 + slot][64] swizzled
    __shared__ __align__(16) unsigned short tscr[9][1024];
    const int t = threadIdx.x;
    const int lane = t & 63;
    const int w = t >> 6;
    const int rl = lane & 15;
    const int kg = lane >> 4;
    const int b0 = blockIdx.x * 16;

    #pragma unroll
    for (int c6 = 0; c6 < 6; ++c6) {
        int chunk = t + c6 * 576;
        int row = chunk >> 3, f0 = (chunk & 7) * 8;
        short8 v = *(const short8*)(upws + (size_t)b0 * 1728 + chunk * 8);
        *(short8*)&ups[swz(row, f0)] = v;
    }
    __syncthreads();

    const short* gwp = wsp + 122880;
    const float alpha = alphap[0];
    float gbl[4][4];
    #pragma unroll
    for (int mt = 0; mt < 4; ++mt)
        #pragma unroll
        for (int reg = 0; reg < 4; ++reg) gbl[mt][reg] = gb[mt * 16 + kg * 4 + reg];

    const int c = w % 3, wg = w / 3;

    #pragma unroll
    for (int tl = 0; tl < 9; ++tl) {
        int e = (wg * 9 + tl) * 16 + rl;
        int b = e / 27, rem = e % 27, R = rem / 3, q = rem % 3, C = c + 3 * q;
        int rowR = b * 27 + R, rowC = b * 27 + 9 + C, rowB = b * 27 + 18 + R;

        f32x4 acc[4];
        #pragma unroll
        for (int mt = 0; mt < 4; ++mt) acc[mt] = (f32x4)0.f;

        #pragma unroll
        for (int s6 = 0; s6 < 6; ++s6) {
            int seg = s6 >> 1;
            int kkp = (s6 < 4) ? s6 : 4 + 2 * c + (s6 - 4);
            int row = (seg == 0) ? rowR : (seg == 1) ? rowC : rowB;
            int f = (s6 & 1) * 32 + kg * 8;
            short8 bfrag = *(const short8*)&ups[swz(row, f)];
            #pragma unroll
            for (int mt = 0; mt < 4; ++mt) {
                short8 afrag = *(const short8*)(gwp + ((kkp * 4 + mt) * 64 + lane) * 8);
                acc[mt] = __builtin_amdgcn_mfma_f32_16x16x32_bf16(afrag, bfrag, acc[mt], 0, 0, 0);
            }
        }

        #pragma unroll
        for (int mt = 0; mt < 4; ++mt) {
            short4v du4 = *(const short4v*)&ups[swz(rowR, mt * 16 + kg * 4)];
            short4v dc4 = *(const short4v*)&ups[swz(rowC, mt * 16 + kg * 4)];
            #pragma unroll
            for (int reg = 0; reg < 4; ++reg) {
                int fidx = mt * 16 + kg * 4 + reg;
                float g = sigmoidf(acc[mt][reg] + gbl[mt][reg]);
                float duv = bf2f((unsigned short)du4[reg]);
                float dcv = bf2f((unsigned short)dc4[reg]);
                float dbv = bf2f(ups[swz(rowB, (64 * c + fidx) / 3)]);
                tscr[w][swz(rl, fidx)] = f2bf(alpha * g * (duv + dcv + dbv));
            }
        }
        asm volatile("s_waitcnt lgkmcnt(0)" ::: "memory");
        #pragma unroll
        for (int p = 0; p < 2; ++p) {
            int cl = p * 8 + (lane >> 3), f0 = (lane & 7) * 8;
            int e2 = (wg * 9 + tl) * 16 + cl;
            int b2 = e2 / 27, rem2 = e2 % 27, R2 = rem2 / 3, C2 = c + 3 * (rem2 % 3);
            short8 tv = *(const short8*)&tscr[w][swz(cl, f0)];
            const float* zp = z + (size_t)(b0 + b2) * 5184 + (size_t)(R2 * 9 + C2) * 64 + f0;
            float4 z0 = *(const float4*)zp;
            float4 z1 = *(const float4*)(zp + 4);
            float4 o0, o1;
            o0.x = z0.x + bf2f((unsigned short)tv[0]);
            o0.y = z0.y + bf2f((unsigned short)tv[1]);
            o0.z = z0.z + bf2f((unsigned short)tv[2]);
            o0.w = z0.w + bf2f((unsigned short)tv[3]);
            o1.x = z1.x + bf2f((unsigned short)tv[4]);
            o1.y = z1.y + bf2f((unsigned short)tv[5]);
            o1.z = z1.z + bf2f((unsigned short)tv[6]);
            o1.w = z1.w + bf2f((unsigned short)tv[7]);
            float* op = out + (size_t)(b0 + b2) * 5184 + (size_t)(R2 * 9 + C2) * 64 + f0;
            *(float4*)op = o0;
            *(float4*)(op + 4) = o1;
        }
        asm volatile("s_waitcnt lgkmcnt(0)" ::: "memory");
    }
}

extern "C" void kernel_launch(void* const* d_in, const int* in_sizes, int n_in,
                              void* d_out, int out_size, void* d_ws, size_t ws_size,
                              hipStream_t stream) {
    const float* z   = (const float*)d_in[0];
    const float* w1r = (const float*)d_in[1];
    const float* b1r = (const float*)d_in[2];
    const float* w2r = (const float*)d_in[3];
    const float* b2r = (const float*)d_in[4];
    const float* w1c = (const float*)d_in[5];
    const float* b1c = (const float*)d_in[6];
    const float* w2c = (const float*)d_in[7];
    const float* b2c = (const float*)d_in[8];
    const float* w1b = (const float*)d_in[9];
    const float* b1b = (const float*)d_in[10];
    const float* w2b = (const float*)d_in[11];
    const float* b2b = (const float*)d_in[12];
    const float* gw  = (const float*)d_in[13];
    const float* gb  = (const float*)d_in[14];
    const float* al  = (const float*)d_in[15];
    float* outp = (float*)d_out;
    unsigned short* ws = (unsigned short*)d_ws;

    prepack_kernel<<<70, 256, 0, stream>>>(w1r, w1c, w1b, w2r, w2c, w2b, gw, ws);

    const int Btot = in_sizes[0] / 5184;    // 8192
    unsigned short* upws = ws + UPWS_OFF;
    k1_mlp<<<Btot / 8, 512, 0, stream>>>(z, b1r, b2r, b1c, b2c, b1b, b2b,
                                         (const short*)ws, upws);
    k2_gate<<<Btot / 16, 576, 0, stream>>>(z, upws, (const short*)ws, gb, al, outp);
}